// Round 8
// baseline (187.624 us; speedup 1.0000x reference)
//
#include <hip/hip_runtime.h>
#include <stdint.h>

typedef float  f32x4  __attribute__((ext_vector_type(4)));
typedef float  f32x16 __attribute__((ext_vector_type(16)));
typedef short  s16x8  __attribute__((ext_vector_type(8)));
typedef unsigned short u16x4 __attribute__((ext_vector_type(4)));
typedef unsigned int   u32x2 __attribute__((ext_vector_type(2)));

#define LPAD 2052   // L + 4 padded positions per batch row

__device__ __forceinline__ float bf2f(unsigned short u){
  unsigned v = ((unsigned)u) << 16;
  return __builtin_bit_cast(float, v);
}
__device__ __forceinline__ unsigned short f2bf(float f){
  unsigned u = __builtin_bit_cast(unsigned, f);
  u += 0x7fffu + ((u >> 16) & 1u);
  return (unsigned short)(u >> 16);
}
__device__ __forceinline__ unsigned cvt_pk_bf16(float lo, float hi){
  unsigned r;
  asm volatile("v_cvt_pk_bf16_f32 %0, %1, %2" : "=v"(r) : "v"(lo), "v"(hi));
  return r;
}

// ---------------- K0: fp32 -> bf16 convert (vectorized; used for Wd only) ----------------
__global__ void k_cvt(const float* __restrict__ src, unsigned short* __restrict__ dst, int n4){
  int i = blockIdx.x * 256 + threadIdx.x;
  if (i >= n4) return;
  f32x4 v = ((const f32x4*)src)[i];
  u16x4 o;
  o[0] = f2bf(v[0]); o[1] = f2bf(v[1]); o[2] = f2bf(v[2]); o[3] = f2bf(v[3]);
  ((u16x4*)dst)[i] = o;
}

// ---------------- K0b: write identity pad matrices ----------------
__global__ void k_eye(unsigned short* __restrict__ H){
  int t = blockIdx.x * 256 + threadIdx.x;       // B*4*1024 = 32768
  int b = t >> 12;
  int r = t & 4095;
  int which = r >> 10;
  int ij = r & 1023;
  int p = (which < 2) ? which : (2048 + which);
  H[((size_t)(b * LPAD + p) << 10) + ij] = ((ij >> 5) == (ij & 31)) ? 0x3F80 : 0;
}

// ---------------- K_wprep: Wa2g[col][k] = bf16(Wa[f][k*5+kk]), col=f*5+kk<25 else 0 ----
__global__ void k_wprep(const float* __restrict__ Wa, unsigned short* __restrict__ Wa2g){
  int t = blockIdx.x * 256 + threadIdx.x;       // 32768 = 32*1024
  int col = t >> 10, k = t & 1023;
  int f = col / 5, kk = col - 5 * f;
  unsigned short v = 0;
  if (col < 25) v = f2bf(Wa[f * 5120 + k * 5 + kk]);
  Wa2g[t] = v;
}

// ---------------- K1: 256x256 8-phase GEMM, A = fp32 X reg-staged + cvt fused ----
#define MFMA16 __builtin_amdgcn_mfma_f32_16x16x32_bf16

__global__ __launch_bounds__(512, 2) void k_gemm8(const float* __restrict__ X,         // [16384][1024] fp32
                                                  const unsigned short* __restrict__ Bw,// [1024][1024] bf16
                                                  const float* __restrict__ bias,
                                                  unsigned short* __restrict__ H){
  __shared__ __align__(128) unsigned short lds[65536];  // 128 KB, 2 buffers
  const int tid = threadIdx.x;
  const int wid = tid >> 6, l = tid & 63;
  const int wm2 = wid >> 2, wn2 = wid & 3;
  const int lm = l & 15, lk = l >> 4;
  const int hb = blockIdx.x;                 // 0..255
  const int xcd = hb & 7, sl = hb >> 3;      // 0..31
  const int bm = xcd * 8 + (sl >> 2), bn = sl & 3;
  const int M0 = bm * 256, N0 = bn * 256;

  // LDS swizzle: 16B chunk c of row r stored at chunk c^(r&7)
  const unsigned ko0 = (unsigned)((lk ^ (lm & 7)) << 4);
  const unsigned ko1 = ko0 ^ 64u;
  const unsigned aB0 = (unsigned)wm2 * 16384;
  const unsigned bB0 = 32768u + (unsigned)(wn2 >> 1) * 16384;
  const unsigned rB  = (((unsigned)(wn2 & 1)) * 64 + lm) * 128;
  const unsigned rA  = (unsigned)lm * 128;

  f32x4 acc[8][4] = {};
  s16x8 af[4][2], bf0[2][2], bf1[2][2];
  f32x4 axr[8];    // reg-staged fp32 A tile slice (8 x 16B per thread)

  // per-thread A addressing: j-th load covers floats f=(j*512+tid)*4 of the 256x64 tile
  // row = e>>4, col0 = (e&15)*4  (e = j*512+tid)
  #define AL_TILE(kt) { const int ktK = (kt) * 64; _Pragma("unroll")                  \
    for (int j = 0; j < 8; j++){                                                      \
      unsigned e = (unsigned)(j * 512 + tid);                                         \
      axr[j] = *(const f32x4*)(X + (size_t)(M0 + (e >> 4)) * 1024 + ktK + (e & 15u) * 4u); } }

  #define AW_TILE(bufbase) { _Pragma("unroll")                                        \
    for (int j = 0; j < 8; j++){                                                      \
      unsigned e = (unsigned)(j * 512 + tid);                                         \
      unsigned row = e >> 4;                                                          \
      unsigned half = row >> 7, r7 = row & 127u;                                      \
      unsigned chunk = (e & 15u) >> 1;                                                \
      unsigned off = (e & 1u) * 8u;                                                   \
      unsigned d = (bufbase) + half * 16384u + r7 * 128u                              \
                   + ((chunk ^ (r7 & 7u)) << 4) + off;                                \
      u32x2 pk;                                                                       \
      pk[0] = cvt_pk_bf16(axr[j][0], axr[j][1]);                                      \
      pk[1] = cvt_pk_bf16(axr[j][2], axr[j][3]);                                      \
      *(u32x2*)&lds[d >> 1] = pk; } }

  // B half-tile stage: linear LDS dest, inverse-swizzled global source (2 loads/thread)
  #define BS_HALF(kt, h, bufbase) { const int ktK = (kt) * 64; _Pragma("unroll")      \
    for (int j = 0; j < 2; j++){                                                      \
      unsigned d = (unsigned)(j * 512 + tid) * 16;                                    \
      unsigned row = d >> 7;                                                          \
      unsigned srcC = ((d >> 4) & 7u) ^ (row & 7u);                                   \
      const unsigned short* g = Bw + (size_t)(N0 + (h) * 128 + row) * 1024            \
                                + ktK + srcC * 8;                                     \
      __builtin_amdgcn_global_load_lds(                                               \
        (const __attribute__((address_space(1))) void*)g,                             \
        (__attribute__((address_space(3))) void*)&lds[((bufbase) + 32768u + (h) * 16384u + d) >> 1], \
        16, 0, 0); } }

  #define RD_A(mh) { _Pragma("unroll")                                                \
    for (int m = 0; m < 4; m++){                                                      \
      af[m][0] = *(const s16x8*)&lds[(aB + rA + ((mh)*4+m)*2048u + ko0) >> 1];        \
      af[m][1] = *(const s16x8*)&lds[(aB + rA + ((mh)*4+m)*2048u + ko1) >> 1]; } }
  #define RD_B(dst, nh) { _Pragma("unroll")                                           \
    for (int n = 0; n < 2; n++){                                                      \
      dst[n][0] = *(const s16x8*)&lds[(bB + rB + ((nh)*2+n)*2048u + ko0) >> 1];       \
      dst[n][1] = *(const s16x8*)&lds[(bB + rB + ((nh)*2+n)*2048u + ko1) >> 1]; } }
  #define MM(mo, no, bfr) { _Pragma("unroll")                                         \
    for (int m = 0; m < 4; m++){ _Pragma("unroll")                                    \
      for (int n = 0; n < 2; n++){                                                    \
        acc[(mo)+m][(no)+n] = MFMA16(af[m][0], bfr[n][0], acc[(mo)+m][(no)+n], 0,0,0);  \
        acc[(mo)+m][(no)+n] = MFMA16(af[m][1], bfr[n][1], acc[(mo)+m][(no)+n], 0,0,0); } } }
  #define SB0   __builtin_amdgcn_sched_barrier(0);
  #define BARA    { __builtin_amdgcn_s_barrier(); asm volatile("s_waitcnt lgkmcnt(0)":::"memory"); SB0 }
  #define BARA_NL { __builtin_amdgcn_s_barrier(); SB0 }
  #define BARB    { __builtin_amdgcn_s_barrier(); SB0 }

  // ---- prologue: tile 0 into buf0 ----
  AL_TILE(0); SB0
  BS_HALF(0, 0, 0u); BS_HALF(0, 1, 0u); SB0
  asm volatile("s_waitcnt vmcnt(4)" ::: "memory"); SB0   // A loads (oldest 8 of 12) retired
  AW_TILE(0u); SB0
  asm volatile("s_waitcnt vmcnt(0) lgkmcnt(0)" ::: "memory");
  __builtin_amdgcn_s_barrier(); SB0

  #pragma unroll 1
  for (int i = 0; i < 8; i++){
    const int ktA = 2 * i + 1;     // -> buf1, staged P1-P3
    const int ktB = 2 * i + 2;     // -> buf0, staged P5-P7
    unsigned aB = aB0, bB = bB0;   // compute buf0
    // P1
    RD_A(0); RD_B(bf0, 0);
    if (ktA < 16){ AL_TILE(ktA); SB0 BS_HALF(ktA, 0, 65536u); }
    BARA; __builtin_amdgcn_s_setprio(1); MM(0, 0, bf0); __builtin_amdgcn_s_setprio(0); BARB;
    // P2
    RD_B(bf1, 1);
    if (ktA < 16){ BS_HALF(ktA, 1, 65536u); }
    BARA; __builtin_amdgcn_s_setprio(1); MM(0, 2, bf1); __builtin_amdgcn_s_setprio(0); BARB;
    // P3
    RD_A(1);
    if (ktA < 16){
      asm volatile("s_waitcnt vmcnt(4)" ::: "memory"); SB0   // retire AL(ktA), leave BS(ktA)x4
      AW_TILE(65536u);
    }
    BARA; __builtin_amdgcn_s_setprio(1); MM(4, 2, bf1); __builtin_amdgcn_s_setprio(0); BARB;
    // P4
    BARA_NL; __builtin_amdgcn_s_setprio(1); MM(4, 0, bf0); __builtin_amdgcn_s_setprio(0);
    asm volatile("s_waitcnt vmcnt(0)" ::: "memory");         // drain BS(ktA)x4 (2.5-3.5 ph lead)
    BARB;
    // P5-P8: compute buf1, stage ktB -> buf0
    aB = 65536u + aB0; bB = 65536u + bB0;
    RD_A(0); RD_B(bf0, 0);
    if (ktB < 16){ AL_TILE(ktB); SB0 BS_HALF(ktB, 0, 0u); }
    BARA; __builtin_amdgcn_s_setprio(1); MM(0, 0, bf0); __builtin_amdgcn_s_setprio(0); BARB;
    RD_B(bf1, 1);
    if (ktB < 16){ BS_HALF(ktB, 1, 0u); }
    BARA; __builtin_amdgcn_s_setprio(1); MM(0, 2, bf1); __builtin_amdgcn_s_setprio(0); BARB;
    RD_A(1);
    if (ktB < 16){
      asm volatile("s_waitcnt vmcnt(4)" ::: "memory"); SB0
      AW_TILE(0u);
    }
    BARA; __builtin_amdgcn_s_setprio(1); MM(4, 2, bf1); __builtin_amdgcn_s_setprio(0); BARB;
    BARA_NL; __builtin_amdgcn_s_setprio(1); MM(4, 0, bf0); __builtin_amdgcn_s_setprio(0);
    asm volatile("s_waitcnt vmcnt(0)" ::: "memory");
    BARB;
  }

  // epilogue: h = acc + bias -> bf16 H
  float bv[4];
  #pragma unroll
  for (int n = 0; n < 4; n++) bv[n] = bias[N0 + wn2 * 64 + n * 16 + lm];
  #pragma unroll
  for (int m = 0; m < 8; m++){
    #pragma unroll
    for (int r = 0; r < 4; r++){
      int gm = M0 + wm2 * 128 + m * 16 + lk * 4 + r;
      int bb = gm >> 11, li = gm & 2047;
      unsigned short* orow = H + ((size_t)(bb * LPAD + 2 + li) << 10);
      #pragma unroll
      for (int n = 0; n < 4; n++){
        orow[N0 + wn2 * 64 + n * 16 + lm] = f2bf(acc[m][n][r] + bv[n]);
      }
    }
  }
  #undef AL_TILE
  #undef AW_TILE
  #undef BS_HALF
  #undef RD_A
  #undef RD_B
  #undef MM
  #undef SB0
  #undef BARA
  #undef BARA_NL
  #undef BARB
}

// ---------------- K2: part[p][0..31] = <Hpad[p], Wa2g[col]>  (thin MFMA GEMM) ----------------
__global__ __launch_bounds__(256) void k_part(const unsigned short* __restrict__ H,    // [16416][1024]
                                              const unsigned short* __restrict__ Wa2g, // [32][1024]
                                              float* __restrict__ part){               // [16512][32]
  __shared__ unsigned short sB[32768];  // [32 col][1024 k], chunk c at c^(col&7)
  const int tid = threadIdx.x;
  const int wv = tid >> 6, l = tid & 63;
  const int lm = l & 15, lk = l >> 4;
  #pragma unroll
  for (int j = 0; j < 16; j++){
    unsigned d = (unsigned)(j * 256 + tid) * 16;
    unsigned col = d >> 11;
    unsigned srcC = ((d >> 4) & 127u) ^ (col & 7u);
    const unsigned short* g = Wa2g + col * 1024 + srcC * 8;
    __builtin_amdgcn_global_load_lds((const __attribute__((address_space(1))) void*)g,
                                     (__attribute__((address_space(3))) void*)&sB[d >> 1],
                                     16, 0, 0);
  }
  __syncthreads();
  const int rbase = blockIdx.x * 128 + wv * 32;
  f32x4 acc[2][2] = {};
  for (int kk = 0; kk < 1024; kk += 32){
    s16x8 aF[2], bF[2];
    #pragma unroll
    for (int m = 0; m < 2; m++)
      aF[m] = *(const s16x8*)(H + (size_t)(rbase + m * 16 + lm) * 1024 + kk + lk * 8);
    #pragma unroll
    for (int n = 0; n < 2; n++){
      unsigned col = (unsigned)(n * 16 + lm);
      unsigned c = (unsigned)(kk >> 3) + (unsigned)lk;
      bF[n] = *(const s16x8*)&sB[(col * 2048u + ((c ^ (col & 7u)) << 4)) >> 1];
    }
    #pragma unroll
    for (int m = 0; m < 2; m++){
      #pragma unroll
      for (int n = 0; n < 2; n++)
        acc[m][n] = MFMA16(aF[m], bF[n], acc[m][n], 0, 0, 0);
    }
  }
  #pragma unroll
  for (int m = 0; m < 2; m++){
    #pragma unroll
    for (int r = 0; r < 4; r++){
      int row = rbase + m * 16 + lk * 4 + r;
      #pragma unroll
      for (int n = 0; n < 2; n++)
        part[(size_t)row * 32 + n * 16 + lm] = acc[m][n][r];
    }
  }
}

// ---------------- K3: scores -> leaky_relu -> softmax -> s = prod(alpha) ----------------
__global__ void k_alpha(const float* __restrict__ part, const float* __restrict__ battn,
                        float* __restrict__ sprod){
  int t = blockIdx.x * 256 + threadIdx.x;
  if (t >= 16384) return;
  int bb = t >> 11, li = t & 2047;
  int pbase = bb * LPAD + li;
  float sc[5];
  #pragma unroll
  for (int f = 0; f < 5; f++){
    float a = battn[f];
    #pragma unroll
    for (int k = 0; k < 5; k++)
      a += part[(size_t)(pbase + k) * 32 + f * 5 + k];
    sc[f] = (a > 0.f) ? a : 0.01f * a;
  }
  float m = sc[0];
  #pragma unroll
  for (int f = 1; f < 5; f++) m = fmaxf(m, sc[f]);
  float e0 = expf(sc[0] - m), e1 = expf(sc[1] - m), e2 = expf(sc[2] - m),
        e3 = expf(sc[3] - m), e4 = expf(sc[4] - m);
  float ssum = e0 + e1 + e2 + e3 + e4;
  float inv = 1.f / ssum;
  float inv2 = inv * inv;
  sprod[t] = (e0 * e1 * e2 * e3 * e4) * inv2 * inv2 * inv;
}

// ---------------- K4: per-position 32x32 matrix chain (MFMA), scaled by s ----------------
__global__ __launch_bounds__(256) void k_chain(const unsigned short* __restrict__ H,
                                               const float* __restrict__ sp,
                                               float* __restrict__ out){
  const int tid = threadIdx.x;
  const int w = tid >> 6, l = tid & 63;
  const int blk = (blockIdx.x & 7) * 512 + (blockIdx.x >> 3);
  const int pos = blk * 4 + w;
  const int bb = pos >> 11, li = pos & 2047;
  const unsigned short* hbase = H + ((size_t)(bb * LPAD + li) << 10);
  const int col = l & 31;
  const int kh = (l >> 5) << 3;

  const unsigned short* h4 = hbase + 4 * 1024;
  unsigned q0, q1, q2, q3, q4, q5, q6, q7;
  {
    #define LD2(kk) ((unsigned)h4[(kk) * 32 + col] | ((unsigned)h4[((kk) + 1) * 32 + col] << 16))
    q0 = LD2(kh + 0);  q1 = LD2(kh + 2);  q2 = LD2(kh + 4);  q3 = LD2(kh + 6);
    q4 = LD2(kh + 16); q5 = LD2(kh + 18); q6 = LD2(kh + 20); q7 = LD2(kh + 22);
    #undef LD2
  }
  union { unsigned u[4]; s16x8 v; } ub0, ub1;
  ub0.u[0] = q0; ub0.u[1] = q1; ub0.u[2] = q2; ub0.u[3] = q3;
  ub1.u[0] = q4; ub1.u[1] = q5; ub1.u[2] = q6; ub1.u[3] = q7;
  s16x8 Bf0 = ub0.v, Bf1 = ub1.v;

  f32x16 acc;
  #pragma unroll
  for (int st = 0; st < 4; st++){
    const int km = 3 - st;
    const unsigned short* hA = hbase + (km << 10);
    s16x8 A0 = *(const s16x8*)(hA + col * 32 + kh);
    s16x8 A1 = *(const s16x8*)(hA + col * 32 + kh + 16);
    f32x16 z = {0,0,0,0,0,0,0,0,0,0,0,0,0,0,0,0};
    acc = __builtin_amdgcn_mfma_f32_32x32x16_bf16(A0, Bf0, z,   0, 0, 0);
    acc = __builtin_amdgcn_mfma_f32_32x32x16_bf16(A1, Bf1, acc, 0, 0, 0);
    if (st < 3){
      unsigned d0 = cvt_pk_bf16(acc[0],  acc[1]);
      unsigned d1 = cvt_pk_bf16(acc[2],  acc[3]);
      unsigned d2 = cvt_pk_bf16(acc[4],  acc[5]);
      unsigned d3 = cvt_pk_bf16(acc[6],  acc[7]);
      unsigned d4 = cvt_pk_bf16(acc[8],  acc[9]);
      unsigned d5 = cvt_pk_bf16(acc[10], acc[11]);
      unsigned d6 = cvt_pk_bf16(acc[12], acc[13]);
      unsigned d7 = cvt_pk_bf16(acc[14], acc[15]);
      unsigned p0 = __shfl_xor(d0, 32, 64);
      unsigned p1 = __shfl_xor(d1, 32, 64);
      unsigned p2 = __shfl_xor(d2, 32, 64);
      unsigned p3 = __shfl_xor(d3, 32, 64);
      unsigned p4 = __shfl_xor(d4, 32, 64);
      unsigned p5 = __shfl_xor(d5, 32, 64);
      unsigned p6 = __shfl_xor(d6, 32, 64);
      unsigned p7 = __shfl_xor(d7, 32, 64);
      const bool lo = (l < 32);
      ub0.u[0] = lo ? d0 : p2;  ub0.u[1] = lo ? d1 : p3;
      ub0.u[2] = lo ? p0 : d2;  ub0.u[3] = lo ? p1 : d3;
      ub1.u[0] = lo ? d4 : p6;  ub1.u[1] = lo ? d5 : p7;
      ub1.u[2] = lo ? p4 : d6;  ub1.u[3] = lo ? p5 : d7;
      Bf0 = ub0.v; Bf1 = ub1.v;
    }
  }

  const float sv = sp[pos];
  float* ob = out + ((size_t)pos << 10);
  #pragma unroll
  for (int t = 0; t < 16; t++){
    int row = (t & 3) + 8 * (t >> 2) + ((l >> 5) << 2);
    ob[row * 32 + col] = sv * acc[t];
  }
}

// ---------------- launcher ----------------
extern "C" void kernel_launch(void* const* d_in, const int* in_sizes, int n_in,
                              void* d_out, int out_size, void* d_ws, size_t ws_size,
                              hipStream_t stream){
  const float* X  = (const float*)d_in[0];   // [8][2048][32][32] fp32
  const float* Wd = (const float*)d_in[1];
  const float* bd = (const float*)d_in[2];
  const float* Wa = (const float*)d_in[3];
  const float* ba = (const float*)d_in[4];
  float* out = (float*)d_out;

  char* ws = (char*)d_ws;
  unsigned short* Hpad = (unsigned short*)ws;                               // 33,619,968 B
  unsigned short* Wbf  = (unsigned short*)(ws + 33619968);                  // 2,097,152 B
  float*          sprod= (float*)(ws + 33619968 + 2097152);                 // 65,536 B
  unsigned short* Wa2g = (unsigned short*)(ws + 33619968 + 2097152 + 65536);// 65,536 B
  // scratch parked in d_out (fully rewritten by k_chain):
  float*          part = (float*)((char*)d_out + 33554432);                 // 16512*32*4 B

  k_cvt<<<1024, 256, 0, stream>>>(Wd, Wbf, 262144);
  k_eye<<<128, 256, 0, stream>>>(Hpad);
  k_wprep<<<128, 256, 0, stream>>>(Wa, Wa2g);
  k_gemm8<<<256, 512, 0, stream>>>(X, Wbf, bd, Hpad);
  k_part<<<129, 256, 0, stream>>>(Hpad, Wa2g, part);
  k_alpha<<<64, 256, 0, stream>>>(part, ba, sprod);
  k_chain<<<4096, 256, 0, stream>>>(Hpad, sprod, out);
}

// Round 9
// 98.061 us; speedup vs baseline: 1.9133x; 1.9133x over previous
//
#include <hip/hip_runtime.h>
#include <stdint.h>

typedef float  f32x4  __attribute__((ext_vector_type(4)));
typedef float  f32x16 __attribute__((ext_vector_type(16)));
typedef short  s16x8  __attribute__((ext_vector_type(8)));
typedef unsigned short u16x4 __attribute__((ext_vector_type(4)));

#define LPAD 2052   // L + 4 padded positions per batch row

__device__ __forceinline__ float bf2f(unsigned short u){
  unsigned v = ((unsigned)u) << 16;
  return __builtin_bit_cast(float, v);
}
__device__ __forceinline__ unsigned short f2bf(float f){
  unsigned u = __builtin_bit_cast(unsigned, f);
  u += 0x7fffu + ((u >> 16) & 1u);
  return (unsigned short)(u >> 16);
}
__device__ __forceinline__ unsigned cvt_pk_bf16(float lo, float hi){
  unsigned r;
  asm volatile("v_cvt_pk_bf16_f32 %0, %1, %2" : "=v"(r) : "v"(lo), "v"(hi));
  return r;
}

// ---------------- K0: fp32 -> bf16 convert (vectorized) ----------------
__global__ void k_cvt(const float* __restrict__ src, unsigned short* __restrict__ dst, int n4){
  int i = blockIdx.x * 256 + threadIdx.x;
  if (i >= n4) return;
  f32x4 v = ((const f32x4*)src)[i];
  u16x4 o;
  o[0] = f2bf(v[0]); o[1] = f2bf(v[1]); o[2] = f2bf(v[2]); o[3] = f2bf(v[3]);
  ((u16x4*)dst)[i] = o;
}

// ---------------- K0b: write identity pad matrices ----------------
__global__ void k_eye(unsigned short* __restrict__ H){
  int t = blockIdx.x * 256 + threadIdx.x;       // B*4*1024 = 32768
  int b = t >> 12;
  int r = t & 4095;
  int which = r >> 10;
  int ij = r & 1023;
  int p = (which < 2) ? which : (2048 + which);
  H[((size_t)(b * LPAD + p) << 10) + ij] = ((ij >> 5) == (ij & 31)) ? 0x3F80 : 0;
}

// ---------------- K_wprep: Wa2g[col][k] = bf16(Wa[f][k*5+kk]), col=f*5+kk<25 else 0 ----
__global__ void k_wprep(const float* __restrict__ Wa, unsigned short* __restrict__ Wa2g){
  int t = blockIdx.x * 256 + threadIdx.x;       // 32768 = 32*1024
  int col = t >> 10, k = t & 1023;
  int f = col / 5, kk = col - 5 * f;
  unsigned short v = 0;
  if (col < 25) v = f2bf(Wa[f * 5120 + k * 5 + kk]);
  Wa2g[t] = v;
}

// ---------------- K1: 256x256 8-phase GEMM (grid=256, 1 block/CU, row&7 swizzle) ----
// round-7 proven structure; staging quarters moved 1 phase earlier (same vmcnt counts)
#define MFMA16 __builtin_amdgcn_mfma_f32_16x16x32_bf16

__global__ __launch_bounds__(512, 2) void k_gemm8(const unsigned short* __restrict__ A,   // [16384][1024]
                                                  const unsigned short* __restrict__ Bw,  // [1024][1024]
                                                  const float* __restrict__ bias,
                                                  unsigned short* __restrict__ H){
  __shared__ __align__(128) unsigned short lds[65536];  // 128 KB
  const int tid = threadIdx.x;
  const int wid = tid >> 6, l = tid & 63;
  const int wm2 = wid >> 2, wn2 = wid & 3;
  const int lm = l & 15, lk = l >> 4;
  const int hb = blockIdx.x;                 // 0..255
  const int xcd = hb & 7, sl = hb >> 3;      // 0..31
  const int bm = xcd * 8 + (sl >> 2), bn = sl & 3;
  const int M0 = bm * 256, N0 = bn * 256;

  // swizzle: element chunk c (16B) of row stored at chunk c ^ (row&7)
  const unsigned ko0 = (unsigned)((lk ^ (lm & 7)) << 4);
  const unsigned ko1 = ko0 ^ 64u;
  const unsigned aB0 = (unsigned)wm2 * 16384;
  const unsigned bB0 = 32768u + (unsigned)(wn2 >> 1) * 16384;
  const unsigned rB  = (((unsigned)(wn2 & 1)) * 64 + lm) * 128;  // + n*2048
  const unsigned rA  = (unsigned)lm * 128;                       // + m*2048

  f32x4 acc[8][4] = {};
  s16x8 af[4][2], bf0[2][2], bf1[2][2];

  // stage one 16KB half-tile: linear LDS dest, inverse-swizzled global source
  #define STAGE_HALF(panelRow, mat, bufbase)                                         \
    { _Pragma("unroll")                                                              \
      for (int j = 0; j < 2; j++){                                                   \
        unsigned d = (unsigned)(j * 512 + tid) * 16;                                 \
        unsigned row = d >> 7;                                                       \
        unsigned srcC = ((d >> 4) & 7u) ^ (row & 7u);                                \
        const unsigned short* g = (mat) + (size_t)((panelRow) + row) * 1024          \
                                  + ktK + srcC * 8;                                  \
        __builtin_amdgcn_global_load_lds(                                            \
          (const __attribute__((address_space(1))) void*)g,                          \
          (__attribute__((address_space(3))) void*)&lds[((bufbase) + d) >> 1],       \
          16, 0, 0);                                                                 \
      } }
  #define STAGE_Q(b, kt, q)                                                          \
    { const int ktK = (kt) * 64;                                                     \
      if ((q) == 0)      STAGE_HALF(M0,       A,  (b)*65536u)                        \
      else if ((q) == 1) STAGE_HALF(M0+128,   A,  (b)*65536u+16384u)                 \
      else if ((q) == 2) STAGE_HALF(N0,       Bw, (b)*65536u+32768u)                 \
      else               STAGE_HALF(N0+128,   Bw, (b)*65536u+49152u) }

  #define RD_A(mh) { _Pragma("unroll")                                               \
    for (int m = 0; m < 4; m++){                                                     \
      af[m][0] = *(const s16x8*)&lds[(aB + rA + ((mh)*4+m)*2048u + ko0) >> 1];       \
      af[m][1] = *(const s16x8*)&lds[(aB + rA + ((mh)*4+m)*2048u + ko1) >> 1]; } }
  #define RD_B(dst, nh) { _Pragma("unroll")                                          \
    for (int n = 0; n < 2; n++){                                                     \
      dst[n][0] = *(const s16x8*)&lds[(bB + rB + ((nh)*2+n)*2048u + ko0) >> 1];      \
      dst[n][1] = *(const s16x8*)&lds[(bB + rB + ((nh)*2+n)*2048u + ko1) >> 1]; } }
  #define MM(mo, no, bfr) { _Pragma("unroll")                                        \
    for (int m = 0; m < 4; m++){ _Pragma("unroll")                                   \
      for (int n = 0; n < 2; n++){                                                   \
        acc[(mo)+m][(no)+n] = MFMA16(af[m][0], bfr[n][0], acc[(mo)+m][(no)+n], 0,0,0); \
        acc[(mo)+m][(no)+n] = MFMA16(af[m][1], bfr[n][1], acc[(mo)+m][(no)+n], 0,0,0); } } }
  #define BARA    { __builtin_amdgcn_s_barrier(); asm volatile("s_waitcnt lgkmcnt(0)":::"memory"); __builtin_amdgcn_sched_barrier(0); }
  #define BARA_NL { __builtin_amdgcn_s_barrier(); __builtin_amdgcn_sched_barrier(0); }
  #define BARB    { __builtin_amdgcn_s_barrier(); __builtin_amdgcn_sched_barrier(0); }

  // prologue: kt0 full (8 loads) + kt1.h0 (2 loads); wait kt0 -> vmcnt(2)
  STAGE_Q(0, 0, 0); STAGE_Q(0, 0, 1); STAGE_Q(0, 0, 2); STAGE_Q(0, 0, 3);
  __builtin_amdgcn_sched_barrier(0);
  STAGE_Q(1, 1, 0);
  __builtin_amdgcn_sched_barrier(0);
  asm volatile("s_waitcnt vmcnt(2)" ::: "memory");
  __builtin_amdgcn_s_barrier();
  __builtin_amdgcn_sched_barrier(0);

  #pragma unroll 1
  for (int i = 0; i < 8; i++){
    const int ktA = 2 * i + 1;
    const int ktB = 2 * i + 2;
    const int ktC = 2 * i + 3;
    unsigned aB = aB0, bB = bB0;   // buf0
    // ph1: stage q1+q2 of ktA (leads 3 phases to end-P4 wait)
    RD_A(0); RD_B(bf0, 0);
    STAGE_Q(1, ktA, 1); STAGE_Q(1, ktA, 2);
    BARA; __builtin_amdgcn_s_setprio(1); MM(0, 0, bf0); __builtin_amdgcn_s_setprio(0); BARB;
    // ph2: stage q3 of ktA (2-phase lead)
    RD_B(bf1, 1);
    STAGE_Q(1, ktA, 3);
    BARA; __builtin_amdgcn_s_setprio(1); MM(0, 2, bf1); __builtin_amdgcn_s_setprio(0); BARB;
    // ph3: stage q0 of ktB
    RD_A(1);
    if (ktB < 16) STAGE_Q(0, ktB, 0);
    BARA; __builtin_amdgcn_s_setprio(1); MM(4, 2, bf1); __builtin_amdgcn_s_setprio(0); BARB;
    // ph4: no staging; retire ktA (leave ktB q0 in flight)
    BARA_NL; __builtin_amdgcn_s_setprio(1); MM(4, 0, bf0); __builtin_amdgcn_s_setprio(0);
    if (i == 7) { asm volatile("s_waitcnt vmcnt(0)" ::: "memory"); }
    else        { asm volatile("s_waitcnt vmcnt(2)" ::: "memory"); }
    BARB;
    // ph5-8 on buf1
    aB = 65536u + aB0; bB = 65536u + bB0;
    RD_A(0); RD_B(bf0, 0);
    if (ktB < 16){ STAGE_Q(0, ktB, 1); STAGE_Q(0, ktB, 2); }
    BARA; __builtin_amdgcn_s_setprio(1); MM(0, 0, bf0); __builtin_amdgcn_s_setprio(0); BARB;
    RD_B(bf1, 1);
    if (ktB < 16) STAGE_Q(0, ktB, 3);
    BARA; __builtin_amdgcn_s_setprio(1); MM(0, 2, bf1); __builtin_amdgcn_s_setprio(0); BARB;
    RD_A(1);
    if (ktC < 16) STAGE_Q(1, ktC, 0);
    BARA; __builtin_amdgcn_s_setprio(1); MM(4, 2, bf1); __builtin_amdgcn_s_setprio(0); BARB;
    BARA_NL; __builtin_amdgcn_s_setprio(1); MM(4, 0, bf0); __builtin_amdgcn_s_setprio(0);
    if (i < 7) { asm volatile("s_waitcnt vmcnt(2)" ::: "memory"); }
    BARB;
  }

  // epilogue: h = acc + bias -> bf16 H
  float bv[4];
  #pragma unroll
  for (int n = 0; n < 4; n++) bv[n] = bias[N0 + wn2 * 64 + n * 16 + lm];
  #pragma unroll
  for (int m = 0; m < 8; m++){
    #pragma unroll
    for (int r = 0; r < 4; r++){
      int gm = M0 + wm2 * 128 + m * 16 + lk * 4 + r;
      int bb = gm >> 11, li = gm & 2047;
      unsigned short* orow = H + ((size_t)(bb * LPAD + 2 + li) << 10);
      #pragma unroll
      for (int n = 0; n < 4; n++){
        orow[N0 + wn2 * 64 + n * 16 + lm] = f2bf(acc[m][n][r] + bv[n]);
      }
    }
  }
  #undef STAGE_HALF
  #undef STAGE_Q
  #undef RD_A
  #undef RD_B
  #undef MM
  #undef BARA
  #undef BARA_NL
  #undef BARB
}

// ---------------- K2: part[p][0..31] = <Hpad[p], Wa2g[col]>  (thin MFMA GEMM) ----------------
__global__ __launch_bounds__(256) void k_part(const unsigned short* __restrict__ H,    // [16416][1024]
                                              const unsigned short* __restrict__ Wa2g, // [32][1024]
                                              float* __restrict__ part){               // [16512][32]
  __shared__ unsigned short sB[32768];  // [32 col][1024 k], chunk c at c^(col&7)
  const int tid = threadIdx.x;
  const int wv = tid >> 6, l = tid & 63;
  const int lm = l & 15, lk = l >> 4;
  #pragma unroll
  for (int j = 0; j < 16; j++){
    unsigned d = (unsigned)(j * 256 + tid) * 16;
    unsigned col = d >> 11;
    unsigned srcC = ((d >> 4) & 127u) ^ (col & 7u);
    const unsigned short* g = Wa2g + col * 1024 + srcC * 8;
    __builtin_amdgcn_global_load_lds((const __attribute__((address_space(1))) void*)g,
                                     (__attribute__((address_space(3))) void*)&sB[d >> 1],
                                     16, 0, 0);
  }
  __syncthreads();
  const int rbase = blockIdx.x * 128 + wv * 32;
  f32x4 acc[2][2] = {};
  for (int kk = 0; kk < 1024; kk += 32){
    s16x8 aF[2], bF[2];
    #pragma unroll
    for (int m = 0; m < 2; m++)
      aF[m] = *(const s16x8*)(H + (size_t)(rbase + m * 16 + lm) * 1024 + kk + lk * 8);
    #pragma unroll
    for (int n = 0; n < 2; n++){
      unsigned col = (unsigned)(n * 16 + lm);
      unsigned c = (unsigned)(kk >> 3) + (unsigned)lk;
      bF[n] = *(const s16x8*)&sB[(col * 2048u + ((c ^ (col & 7u)) << 4)) >> 1];
    }
    #pragma unroll
    for (int m = 0; m < 2; m++){
      #pragma unroll
      for (int n = 0; n < 2; n++)
        acc[m][n] = MFMA16(aF[m], bF[n], acc[m][n], 0, 0, 0);
    }
  }
  #pragma unroll
  for (int m = 0; m < 2; m++){
    #pragma unroll
    for (int r = 0; r < 4; r++){
      int row = rbase + m * 16 + lk * 4 + r;
      #pragma unroll
      for (int n = 0; n < 2; n++)
        part[(size_t)row * 32 + n * 16 + lm] = acc[m][n][r];
    }
  }
}

// ---------------- K3: scores -> leaky_relu -> softmax -> s = prod(alpha) ----------------
__global__ void k_alpha(const float* __restrict__ part, const float* __restrict__ battn,
                        float* __restrict__ sprod){
  int t = blockIdx.x * 256 + threadIdx.x;
  if (t >= 16384) return;
  int bb = t >> 11, li = t & 2047;
  int pbase = bb * LPAD + li;
  float sc[5];
  #pragma unroll
  for (int f = 0; f < 5; f++){
    float a = battn[f];
    #pragma unroll
    for (int k = 0; k < 5; k++)
      a += part[(size_t)(pbase + k) * 32 + f * 5 + k];
    sc[f] = (a > 0.f) ? a : 0.01f * a;
  }
  float m = sc[0];
  #pragma unroll
  for (int f = 1; f < 5; f++) m = fmaxf(m, sc[f]);
  float e0 = expf(sc[0] - m), e1 = expf(sc[1] - m), e2 = expf(sc[2] - m),
        e3 = expf(sc[3] - m), e4 = expf(sc[4] - m);
  float ssum = e0 + e1 + e2 + e3 + e4;
  float inv = 1.f / ssum;
  float inv2 = inv * inv;
  sprod[t] = (e0 * e1 * e2 * e3 * e4) * inv2 * inv2 * inv;
}

// ---------------- K4: per-position 32x32 matrix chain (MFMA), scaled by s ----------------
__global__ __launch_bounds__(256) void k_chain(const unsigned short* __restrict__ H,
                                               const float* __restrict__ sp,
                                               float* __restrict__ out){
  const int tid = threadIdx.x;
  const int w = tid >> 6, l = tid & 63;
  const int blk = (blockIdx.x & 7) * 512 + (blockIdx.x >> 3);
  const int pos = blk * 4 + w;
  const int bb = pos >> 11, li = pos & 2047;
  const unsigned short* hbase = H + ((size_t)(bb * LPAD + li) << 10);
  const int col = l & 31;
  const int kh = (l >> 5) << 3;

  const unsigned short* h4 = hbase + 4 * 1024;
  unsigned q0, q1, q2, q3, q4, q5, q6, q7;
  {
    #define LD2(kk) ((unsigned)h4[(kk) * 32 + col] | ((unsigned)h4[((kk) + 1) * 32 + col] << 16))
    q0 = LD2(kh + 0);  q1 = LD2(kh + 2);  q2 = LD2(kh + 4);  q3 = LD2(kh + 6);
    q4 = LD2(kh + 16); q5 = LD2(kh + 18); q6 = LD2(kh + 20); q7 = LD2(kh + 22);
    #undef LD2
  }
  union { unsigned u[4]; s16x8 v; } ub0, ub1;
  ub0.u[0] = q0; ub0.u[1] = q1; ub0.u[2] = q2; ub0.u[3] = q3;
  ub1.u[0] = q4; ub1.u[1] = q5; ub1.u[2] = q6; ub1.u[3] = q7;
  s16x8 Bf0 = ub0.v, Bf1 = ub1.v;

  f32x16 acc;
  #pragma unroll
  for (int st = 0; st < 4; st++){
    const int km = 3 - st;
    const unsigned short* hA = hbase + (km << 10);
    s16x8 A0 = *(const s16x8*)(hA + col * 32 + kh);
    s16x8 A1 = *(const s16x8*)(hA + col * 32 + kh + 16);
    f32x16 z = {0,0,0,0,0,0,0,0,0,0,0,0,0,0,0,0};
    acc = __builtin_amdgcn_mfma_f32_32x32x16_bf16(A0, Bf0, z,   0, 0, 0);
    acc = __builtin_amdgcn_mfma_f32_32x32x16_bf16(A1, Bf1, acc, 0, 0, 0);
    if (st < 3){
      unsigned d0 = cvt_pk_bf16(acc[0],  acc[1]);
      unsigned d1 = cvt_pk_bf16(acc[2],  acc[3]);
      unsigned d2 = cvt_pk_bf16(acc[4],  acc[5]);
      unsigned d3 = cvt_pk_bf16(acc[6],  acc[7]);
      unsigned d4 = cvt_pk_bf16(acc[8],  acc[9]);
      unsigned d5 = cvt_pk_bf16(acc[10], acc[11]);
      unsigned d6 = cvt_pk_bf16(acc[12], acc[13]);
      unsigned d7 = cvt_pk_bf16(acc[14], acc[15]);
      unsigned p0 = __shfl_xor(d0, 32, 64);
      unsigned p1 = __shfl_xor(d1, 32, 64);
      unsigned p2 = __shfl_xor(d2, 32, 64);
      unsigned p3 = __shfl_xor(d3, 32, 64);
      unsigned p4 = __shfl_xor(d4, 32, 64);
      unsigned p5 = __shfl_xor(d5, 32, 64);
      unsigned p6 = __shfl_xor(d6, 32, 64);
      unsigned p7 = __shfl_xor(d7, 32, 64);
      const bool lo = (l < 32);
      ub0.u[0] = lo ? d0 : p2;  ub0.u[1] = lo ? d1 : p3;
      ub0.u[2] = lo ? p0 : d2;  ub0.u[3] = lo ? p1 : d3;
      ub1.u[0] = lo ? d4 : p6;  ub1.u[1] = lo ? d5 : p7;
      ub1.u[2] = lo ? p4 : d6;  ub1.u[3] = lo ? p5 : d7;
      Bf0 = ub0.v; Bf1 = ub1.v;
    }
  }

  const float sv = sp[pos];
  float* ob = out + ((size_t)pos << 10);
  #pragma unroll
  for (int t = 0; t < 16; t++){
    int row = (t & 3) + 8 * (t >> 2) + ((l >> 5) << 2);
    ob[row * 32 + col] = sv * acc[t];
  }
}

// ---------------- launcher ----------------
extern "C" void kernel_launch(void* const* d_in, const int* in_sizes, int n_in,
                              void* d_out, int out_size, void* d_ws, size_t ws_size,
                              hipStream_t stream){
  const float* X  = (const float*)d_in[0];
  const float* Wd = (const float*)d_in[1];
  const float* bd = (const float*)d_in[2];
  const float* Wa = (const float*)d_in[3];
  const float* ba = (const float*)d_in[4];
  float* out = (float*)d_out;

  char* ws = (char*)d_ws;
  unsigned short* Hpad = (unsigned short*)ws;                               // 33,619,968 B
  unsigned short* Wbf  = (unsigned short*)(ws + 33619968);                  // 2,097,152 B
  float*          sprod= (float*)(ws + 33619968 + 2097152);                 // 65,536 B
  unsigned short* Wa2g = (unsigned short*)(ws + 33619968 + 2097152 + 65536);// 65,536 B
  // scratch parked in d_out (fully rewritten by k_chain):
  unsigned short* Xbf  = (unsigned short*)d_out;                            // [0, 33,554,432)
  float*          part = (float*)((char*)d_out + 33554432);                 // 16512*32*4 B

  k_cvt<<<16384, 256, 0, stream>>>(X, Xbf, 4194304);
  k_cvt<<<1024, 256, 0, stream>>>(Wd, Wbf, 262144);
  k_eye<<<128, 256, 0, stream>>>(Hpad);
  k_wprep<<<128, 256, 0, stream>>>(Wa, Wa2g);
  k_gemm8<<<256, 512, 0, stream>>>(Xbf, Wbf, bd, Hpad);
  k_part<<<129, 256, 0, stream>>>(Hpad, Wa2g, part);
  k_alpha<<<64, 256, 0, stream>>>(part, ba, sprod);
  k_chain<<<4096, 256, 0, stream>>>(Hpad, sprod, out);
}

// Round 11
// 94.575 us; speedup vs baseline: 1.9839x; 1.0369x over previous
//
#include <hip/hip_runtime.h>
#include <stdint.h>

typedef float  f32x4  __attribute__((ext_vector_type(4)));
typedef float  f32x16 __attribute__((ext_vector_type(16)));
typedef short  s16x8  __attribute__((ext_vector_type(8)));
typedef unsigned short u16x4 __attribute__((ext_vector_type(4)));

#define LPAD 2052   // L + 4 padded positions per batch row

__device__ __forceinline__ float bf2f(unsigned short u){
  unsigned v = ((unsigned)u) << 16;
  return __builtin_bit_cast(float, v);
}
__device__ __forceinline__ unsigned short f2bf(float f){
  unsigned u = __builtin_bit_cast(unsigned, f);
  u += 0x7fffu + ((u >> 16) & 1u);
  return (unsigned short)(u >> 16);
}
__device__ __forceinline__ unsigned cvt_pk_bf16(float lo, float hi){
  unsigned r;
  asm volatile("v_cvt_pk_bf16_f32 %0, %1, %2" : "=v"(r) : "v"(lo), "v"(hi));
  return r;
}

// ---------------- K0x: fp32 -> bf16 for X, XCD-aligned ----------------
// block b (lands on XCD b&7) converts A-row (b&7)*2048 + (b>>3), so each XCD's
// L2 ends up holding exactly the 4MB A-slice its k_gemm8 blocks will read.
__global__ void k_cvtx(const float* __restrict__ src, unsigned short* __restrict__ dst){
  int b = blockIdx.x;                        // 16384 blocks = rows
  int bb = (b & 7) * 2048 + (b >> 3);        // bijective
  int i = bb * 256 + threadIdx.x;            // f32x4 chunk index
  f32x4 v = ((const f32x4*)src)[i];
  u16x4 o;
  o[0] = f2bf(v[0]); o[1] = f2bf(v[1]); o[2] = f2bf(v[2]); o[3] = f2bf(v[3]);
  ((u16x4*)dst)[i] = o;
}

// ---------------- K0: fp32 -> bf16 convert (Wd) ----------------
__global__ void k_cvt(const float* __restrict__ src, unsigned short* __restrict__ dst, int n4){
  int i = blockIdx.x * 256 + threadIdx.x;
  if (i >= n4) return;
  f32x4 v = ((const f32x4*)src)[i];
  u16x4 o;
  o[0] = f2bf(v[0]); o[1] = f2bf(v[1]); o[2] = f2bf(v[2]); o[3] = f2bf(v[3]);
  ((u16x4*)dst)[i] = o;
}

// ---------------- K0b: write identity pad matrices ----------------
__global__ void k_eye(unsigned short* __restrict__ H){
  int t = blockIdx.x * 256 + threadIdx.x;       // B*4*1024 = 32768
  int b = t >> 12;
  int r = t & 4095;
  int which = r >> 10;
  int ij = r & 1023;
  int p = (which < 2) ? which : (2048 + which);
  H[((size_t)(b * LPAD + p) << 10) + ij] = ((ij >> 5) == (ij & 31)) ? 0x3F80 : 0;
}

// ---------------- K_wprep: Wa2g[col][e] = bf16(Wa[f][e*5+kk]), col=f*5+kk<25 else 0 ----
__global__ void k_wprep(const float* __restrict__ Wa, unsigned short* __restrict__ Wa2g){
  int t = blockIdx.x * 256 + threadIdx.x;       // 32768 = 32*1024
  int col = t >> 10, e = t & 1023;
  int f = col / 5, kk = col - 5 * f;
  unsigned short v = 0;
  if (col < 25) v = f2bf(Wa[f * 5120 + e * 5 + kk]);
  Wa2g[t] = v;
}

// ---------------- K1: 256x256 8-phase GEMM (grid=256, 1 block/CU, row&7 swizzle) ----
#define MFMA16 __builtin_amdgcn_mfma_f32_16x16x32_bf16

__global__ __launch_bounds__(512, 2) void k_gemm8(const unsigned short* __restrict__ A,   // [16384][1024]
                                                  const unsigned short* __restrict__ Bw,  // [1024][1024]
                                                  const float* __restrict__ bias,
                                                  unsigned short* __restrict__ H){
  __shared__ __align__(128) unsigned short lds[65536];  // 128 KB
  const int tid = threadIdx.x;
  const int wid = tid >> 6, l = tid & 63;
  const int wm2 = wid >> 2, wn2 = wid & 3;
  const int lm = l & 15, lk = l >> 4;
  const int hb = blockIdx.x;                 // 0..255
  const int xcd = hb & 7, sl = hb >> 3;      // 0..31
  const int bm = xcd * 8 + (sl >> 2), bn = sl & 3;
  const int M0 = bm * 256, N0 = bn * 256;

  // swizzle: element chunk c (16B) of row stored at chunk c ^ (row&7)
  const unsigned ko0 = (unsigned)((lk ^ (lm & 7)) << 4);
  const unsigned ko1 = ko0 ^ 64u;
  const unsigned aB0 = (unsigned)wm2 * 16384;
  const unsigned bB0 = 32768u + (unsigned)(wn2 >> 1) * 16384;
  const unsigned rB  = (((unsigned)(wn2 & 1)) * 64 + lm) * 128;  // + n*2048
  const unsigned rA  = (unsigned)lm * 128;                       // + m*2048

  f32x4 acc[8][4] = {};
  s16x8 af[4][2], bf0[2][2], bf1[2][2];

  #define STAGE_HALF(panelRow, mat, bufbase)                                         \
    { _Pragma("unroll")                                                              \
      for (int j = 0; j < 2; j++){                                                   \
        unsigned d = (unsigned)(j * 512 + tid) * 16;                                 \
        unsigned row = d >> 7;                                                       \
        unsigned srcC = ((d >> 4) & 7u) ^ (row & 7u);                                \
        const unsigned short* g = (mat) + (size_t)((panelRow) + row) * 1024          \
                                  + ktK + srcC * 8;                                  \
        __builtin_amdgcn_global_load_lds(                                            \
          (const __attribute__((address_space(1))) void*)g,                          \
          (__attribute__((address_space(3))) void*)&lds[((bufbase) + d) >> 1],       \
          16, 0, 0);                                                                 \
      } }
  #define STAGE_Q(b, kt, q)                                                          \
    { const int ktK = (kt) * 64;                                                     \
      if ((q) == 0)      STAGE_HALF(M0,       A,  (b)*65536u)                        \
      else if ((q) == 1) STAGE_HALF(M0+128,   A,  (b)*65536u+16384u)                 \
      else if ((q) == 2) STAGE_HALF(N0,       Bw, (b)*65536u+32768u)                 \
      else               STAGE_HALF(N0+128,   Bw, (b)*65536u+49152u) }

  #define RD_A(mh) { _Pragma("unroll")                                               \
    for (int m = 0; m < 4; m++){                                                     \
      af[m][0] = *(const s16x8*)&lds[(aB + rA + ((mh)*4+m)*2048u + ko0) >> 1];       \
      af[m][1] = *(const s16x8*)&lds[(aB + rA + ((mh)*4+m)*2048u + ko1) >> 1]; } }
  #define RD_B(dst, nh) { _Pragma("unroll")                                          \
    for (int n = 0; n < 2; n++){                                                     \
      dst[n][0] = *(const s16x8*)&lds[(bB + rB + ((nh)*2+n)*2048u + ko0) >> 1];      \
      dst[n][1] = *(const s16x8*)&lds[(bB + rB + ((nh)*2+n)*2048u + ko1) >> 1]; } }
  #define MM(mo, no, bfr) { _Pragma("unroll")                                        \
    for (int m = 0; m < 4; m++){ _Pragma("unroll")                                   \
      for (int n = 0; n < 2; n++){                                                   \
        acc[(mo)+m][(no)+n] = MFMA16(af[m][0], bfr[n][0], acc[(mo)+m][(no)+n], 0,0,0); \
        acc[(mo)+m][(no)+n] = MFMA16(af[m][1], bfr[n][1], acc[(mo)+m][(no)+n], 0,0,0); } } }
  #define BARA    { __builtin_amdgcn_s_barrier(); asm volatile("s_waitcnt lgkmcnt(0)":::"memory"); __builtin_amdgcn_sched_barrier(0); }
  #define BARA_NL { __builtin_amdgcn_s_barrier(); __builtin_amdgcn_sched_barrier(0); }
  #define BARB    { __builtin_amdgcn_s_barrier(); __builtin_amdgcn_sched_barrier(0); }

  STAGE_Q(0, 0, 0); STAGE_Q(0, 0, 1); STAGE_Q(0, 0, 2); STAGE_Q(0, 0, 3);
  __builtin_amdgcn_sched_barrier(0);
  STAGE_Q(1, 1, 0);
  __builtin_amdgcn_sched_barrier(0);
  asm volatile("s_waitcnt vmcnt(2)" ::: "memory");
  __builtin_amdgcn_s_barrier();
  __builtin_amdgcn_sched_barrier(0);

  #pragma unroll 1
  for (int i = 0; i < 8; i++){
    const int ktA = 2 * i + 1;
    const int ktB = 2 * i + 2;
    const int ktC = 2 * i + 3;
    unsigned aB = aB0, bB = bB0;   // buf0
    RD_A(0); RD_B(bf0, 0);
    STAGE_Q(1, ktA, 1); STAGE_Q(1, ktA, 2);
    BARA; __builtin_amdgcn_s_setprio(1); MM(0, 0, bf0); __builtin_amdgcn_s_setprio(0); BARB;
    RD_B(bf1, 1);
    STAGE_Q(1, ktA, 3);
    BARA; __builtin_amdgcn_s_setprio(1); MM(0, 2, bf1); __builtin_amdgcn_s_setprio(0); BARB;
    RD_A(1);
    if (ktB < 16) STAGE_Q(0, ktB, 0);
    BARA; __builtin_amdgcn_s_setprio(1); MM(4, 2, bf1); __builtin_amdgcn_s_setprio(0); BARB;
    BARA_NL; __builtin_amdgcn_s_setprio(1); MM(4, 0, bf0); __builtin_amdgcn_s_setprio(0);
    if (i == 7) { asm volatile("s_waitcnt vmcnt(0)" ::: "memory"); }
    else        { asm volatile("s_waitcnt vmcnt(2)" ::: "memory"); }
    BARB;
    aB = 65536u + aB0; bB = 65536u + bB0;
    RD_A(0); RD_B(bf0, 0);
    if (ktB < 16){ STAGE_Q(0, ktB, 1); STAGE_Q(0, ktB, 2); }
    BARA; __builtin_amdgcn_s_setprio(1); MM(0, 0, bf0); __builtin_amdgcn_s_setprio(0); BARB;
    RD_B(bf1, 1);
    if (ktB < 16) STAGE_Q(0, ktB, 3);
    BARA; __builtin_amdgcn_s_setprio(1); MM(0, 2, bf1); __builtin_amdgcn_s_setprio(0); BARB;
    RD_A(1);
    if (ktC < 16) STAGE_Q(1, ktC, 0);
    BARA; __builtin_amdgcn_s_setprio(1); MM(4, 2, bf1); __builtin_amdgcn_s_setprio(0); BARB;
    BARA_NL; __builtin_amdgcn_s_setprio(1); MM(4, 0, bf0); __builtin_amdgcn_s_setprio(0);
    if (i < 7) { asm volatile("s_waitcnt vmcnt(2)" ::: "memory"); }
    BARB;
  }

  float bv[4];
  #pragma unroll
  for (int n = 0; n < 4; n++) bv[n] = bias[N0 + wn2 * 64 + n * 16 + lm];
  #pragma unroll
  for (int m = 0; m < 8; m++){
    #pragma unroll
    for (int r = 0; r < 4; r++){
      int gm = M0 + wm2 * 128 + m * 16 + lk * 4 + r;
      int bb = gm >> 11, li = gm & 2047;
      unsigned short* orow = H + ((size_t)(bb * LPAD + 2 + li) << 10);
      #pragma unroll
      for (int n = 0; n < 4; n++){
        orow[N0 + wn2 * 64 + n * 16 + lm] = f2bf(acc[m][n][r] + bv[n]);
      }
    }
  }
  #undef STAGE_HALF
  #undef STAGE_Q
  #undef RD_A
  #undef RD_B
  #undef MM
  #undef BARA
  #undef BARA_NL
  #undef BARB
}

// ---------------- K2: part[p][0..31] = <Hpad[p], Wa2g[col]>  (thin MFMA GEMM) ----------------
__global__ __launch_bounds__(256) void k_part(const unsigned short* __restrict__ H,    // [16416][1024]
                                              const unsigned short* __restrict__ Wa2g, // [32][1024]
                                              float* __restrict__ part){               // [16512][32]
  __shared__ unsigned short sB[32768];  // [32 col][1024 k], chunk c at c^(col&7)
  const int tid = threadIdx.x;
  const int wv = tid >> 6, l = tid & 63;
  const int lm = l & 15, lk = l >> 4;
  #pragma unroll
  for (int j = 0; j < 16; j++){
    unsigned d = (unsigned)(j * 256 + tid) * 16;
    unsigned col = d >> 11;
    unsigned srcC = ((d >> 4) & 127u) ^ (col & 7u);
    const unsigned short* g = Wa2g + col * 1024 + srcC * 8;
    __builtin_amdgcn_global_load_lds((const __attribute__((address_space(1))) void*)g,
                                     (__attribute__((address_space(3))) void*)&sB[d >> 1],
                                     16, 0, 0);
  }
  __syncthreads();
  const int rbase = blockIdx.x * 128 + wv * 32;
  f32x4 acc[2][2] = {};
  for (int kk = 0; kk < 1024; kk += 32){
    s16x8 aF[2], bF[2];
    #pragma unroll
    for (int m = 0; m < 2; m++)
      aF[m] = *(const s16x8*)(H + (size_t)(rbase + m * 16 + lm) * 1024 + kk + lk * 8);
    #pragma unroll
    for (int n = 0; n < 2; n++){
      unsigned col = (unsigned)(n * 16 + lm);
      unsigned c = (unsigned)(kk >> 3) + (unsigned)lk;
      bF[n] = *(const s16x8*)&sB[(col * 2048u + ((c ^ (col & 7u)) << 4)) >> 1];
    }
    #pragma unroll
    for (int m = 0; m < 2; m++){
      #pragma unroll
      for (int n = 0; n < 2; n++)
        acc[m][n] = MFMA16(aF[m], bF[n], acc[m][n], 0, 0, 0);
    }
  }
  #pragma unroll
  for (int m = 0; m < 2; m++){
    #pragma unroll
    for (int r = 0; r < 4; r++){
      int row = rbase + m * 16 + lk * 4 + r;
      #pragma unroll
      for (int n = 0; n < 2; n++)
        part[(size_t)row * 32 + n * 16 + lm] = acc[m][n][r];
    }
  }
}

// ---------------- K4: softmax (from part) + 32x32 matrix chain, scaled by s ----------------
__global__ __launch_bounds__(256) void k_chain(const unsigned short* __restrict__ H,
                                               const float* __restrict__ part,
                                               const float* __restrict__ battn,
                                               float* __restrict__ out){
  const int tid = threadIdx.x;
  const int w = tid >> 6, l = tid & 63;
  const int blk = (blockIdx.x & 7) * 512 + (blockIdx.x >> 3);   // XCD x -> batch x (matches gemm's H writes)
  const int pos = blk * 4 + w;
  const int bb = pos >> 11, li = pos & 2047;
  const unsigned short* hbase = H + ((size_t)(bb * LPAD + li) << 10);
  const int col = l & 31;
  const int kh = (l >> 5) << 3;

  // ---- softmax -> s = prod(alpha) (k_alpha math, per wave; uniform loads) ----
  const float* prow = part + (size_t)(bb * LPAD + li) * 32;
  float sc[5];
  #pragma unroll
  for (int f = 0; f < 5; f++){
    float a = battn[f];
    #pragma unroll
    for (int k = 0; k < 5; k++)
      a += prow[k * 32 + f * 5 + k];
    sc[f] = (a > 0.f) ? a : 0.01f * a;
  }
  float mx = sc[0];
  #pragma unroll
  for (int f = 1; f < 5; f++) mx = fmaxf(mx, sc[f]);
  float e0 = expf(sc[0] - mx), e1 = expf(sc[1] - mx), e2 = expf(sc[2] - mx),
        e3 = expf(sc[3] - mx), e4 = expf(sc[4] - mx);
  float ssum = e0 + e1 + e2 + e3 + e4;
  float inv = 1.f / ssum;
  float inv2 = inv * inv;
  const float sv = (e0 * e1 * e2 * e3 * e4) * inv2 * inv2 * inv;

  // ---- chain ----
  const unsigned short* h4 = hbase + 4 * 1024;
  unsigned q0, q1, q2, q3, q4, q5, q6, q7;
  {
    #define LD2(kk) ((unsigned)h4[(kk) * 32 + col] | ((unsigned)h4[((kk) + 1) * 32 + col] << 16))
    q0 = LD2(kh + 0);  q1 = LD2(kh + 2);  q2 = LD2(kh + 4);  q3 = LD2(kh + 6);
    q4 = LD2(kh + 16); q5 = LD2(kh + 18); q6 = LD2(kh + 20); q7 = LD2(kh + 22);
    #undef LD2
  }
  union { unsigned u[4]; s16x8 v; } ub0, ub1;
  ub0.u[0] = q0; ub0.u[1] = q1; ub0.u[2] = q2; ub0.u[3] = q3;
  ub1.u[0] = q4; ub1.u[1] = q5; ub1.u[2] = q6; ub1.u[3] = q7;
  s16x8 Bf0 = ub0.v, Bf1 = ub1.v;

  f32x16 acc;
  #pragma unroll
  for (int st = 0; st < 4; st++){
    const int km = 3 - st;
    const unsigned short* hA = hbase + (km << 10);
    s16x8 A0 = *(const s16x8*)(hA + col * 32 + kh);
    s16x8 A1 = *(const s16x8*)(hA + col * 32 + kh + 16);
    f32x16 z = {0,0,0,0,0,0,0,0,0,0,0,0,0,0,0,0};
    acc = __builtin_amdgcn_mfma_f32_32x32x16_bf16(A0, Bf0, z,   0, 0, 0);
    acc = __builtin_amdgcn_mfma_f32_32x32x16_bf16(A1, Bf1, acc, 0, 0, 0);
    if (st < 3){
      unsigned d0 = cvt_pk_bf16(acc[0],  acc[1]);
      unsigned d1 = cvt_pk_bf16(acc[2],  acc[3]);
      unsigned d2 = cvt_pk_bf16(acc[4],  acc[5]);
      unsigned d3 = cvt_pk_bf16(acc[6],  acc[7]);
      unsigned d4 = cvt_pk_bf16(acc[8],  acc[9]);
      unsigned d5 = cvt_pk_bf16(acc[10], acc[11]);
      unsigned d6 = cvt_pk_bf16(acc[12], acc[13]);
      unsigned d7 = cvt_pk_bf16(acc[14], acc[15]);
      unsigned p0 = __shfl_xor(d0, 32, 64);
      unsigned p1 = __shfl_xor(d1, 32, 64);
      unsigned p2 = __shfl_xor(d2, 32, 64);
      unsigned p3 = __shfl_xor(d3, 32, 64);
      unsigned p4 = __shfl_xor(d4, 32, 64);
      unsigned p5 = __shfl_xor(d5, 32, 64);
      unsigned p6 = __shfl_xor(d6, 32, 64);
      unsigned p7 = __shfl_xor(d7, 32, 64);
      const bool lo = (l < 32);
      ub0.u[0] = lo ? d0 : p2;  ub0.u[1] = lo ? d1 : p3;
      ub0.u[2] = lo ? p0 : d2;  ub0.u[3] = lo ? p1 : d3;
      ub1.u[0] = lo ? d4 : p6;  ub1.u[1] = lo ? d5 : p7;
      ub1.u[2] = lo ? p4 : d6;  ub1.u[3] = lo ? p5 : d7;
      Bf0 = ub0.v; Bf1 = ub1.v;
    }
  }

  float* ob = out + ((size_t)pos << 10);
  #pragma unroll
  for (int t = 0; t < 16; t++){
    int row = (t & 3) + 8 * (t >> 2) + ((l >> 5) << 2);
    ob[row * 32 + col] = sv * acc[t];
  }
}

// ---------------- launcher ----------------
extern "C" void kernel_launch(void* const* d_in, const int* in_sizes, int n_in,
                              void* d_out, int out_size, void* d_ws, size_t ws_size,
                              hipStream_t stream){
  const float* X  = (const float*)d_in[0];
  const float* Wd = (const float*)d_in[1];
  const float* bd = (const float*)d_in[2];
  const float* Wa = (const float*)d_in[3];
  const float* ba = (const float*)d_in[4];
  float* out = (float*)d_out;

  char* ws = (char*)d_ws;
  unsigned short* Hpad = (unsigned short*)ws;                               // 33,619,968 B
  unsigned short* Wbf  = (unsigned short*)(ws + 33619968);                  // 2,097,152 B
  unsigned short* Wa2g = (unsigned short*)(ws + 33619968 + 2097152);        // 65,536 B
  float*          part = (float*)(ws + 33619968 + 2097152 + 65536);         // 16512*32*4 = 2,113,536 B (ws total ~36.1MB)
  // scratch parked in d_out (consumed by k_gemm8 before k_chain writes):
  unsigned short* Xbf  = (unsigned short*)d_out;                            // [0, 33,554,432)

  k_cvtx<<<16384, 256, 0, stream>>>(X, Xbf);
  k_cvt<<<1024, 256, 0, stream>>>(Wd, Wbf, 262144);
  k_eye<<<128, 256, 0, stream>>>(Hpad);
  k_wprep<<<128, 256, 0, stream>>>(Wa, Wa2g);
  k_gemm8<<<256, 512, 0, stream>>>(Xbf, Wbf, bd, Hpad);
  k_part<<<129, 256, 0, stream>>>(Hpad, Wa2g, part);
  k_chain<<<4096, 256, 0, stream>>>(Hpad, part, ba, out);
}

// Round 12
// 94.530 us; speedup vs baseline: 1.9848x; 1.0005x over previous
//
#include <hip/hip_runtime.h>
#include <stdint.h>

typedef float  f32x4  __attribute__((ext_vector_type(4)));
typedef float  f32x16 __attribute__((ext_vector_type(16)));
typedef short  s16x8  __attribute__((ext_vector_type(8)));
typedef unsigned short u16x4 __attribute__((ext_vector_type(4)));

#define LPAD 2052   // L + 4 padded positions per batch row

__device__ __forceinline__ float bf2f(unsigned short u){
  unsigned v = ((unsigned)u) << 16;
  return __builtin_bit_cast(float, v);
}
__device__ __forceinline__ unsigned short f2bf(float f){
  unsigned u = __builtin_bit_cast(unsigned, f);
  u += 0x7fffu + ((u >> 16) & 1u);
  return (unsigned short)(u >> 16);
}
__device__ __forceinline__ unsigned cvt_pk_bf16(float lo, float hi){
  unsigned r;
  asm volatile("v_cvt_pk_bf16_f32 %0, %1, %2" : "=v"(r) : "v"(lo), "v"(hi));
  return r;
}

// ---------------- K0x: fp32 -> bf16 for X (XCD-aligned remap; perf-neutral, kept) ----
__global__ void k_cvtx(const float* __restrict__ src, unsigned short* __restrict__ dst){
  int b = blockIdx.x;                        // 16384 blocks = rows
  int bb = (b & 7) * 2048 + (b >> 3);        // bijective
  int i = bb * 256 + threadIdx.x;            // f32x4 chunk index
  f32x4 v = ((const f32x4*)src)[i];
  u16x4 o;
  o[0] = f2bf(v[0]); o[1] = f2bf(v[1]); o[2] = f2bf(v[2]); o[3] = f2bf(v[3]);
  ((u16x4*)dst)[i] = o;
}

// ---------------- K0: fp32 -> bf16 convert (Wd) ----------------
__global__ void k_cvt(const float* __restrict__ src, unsigned short* __restrict__ dst, int n4){
  int i = blockIdx.x * 256 + threadIdx.x;
  if (i >= n4) return;
  f32x4 v = ((const f32x4*)src)[i];
  u16x4 o;
  o[0] = f2bf(v[0]); o[1] = f2bf(v[1]); o[2] = f2bf(v[2]); o[3] = f2bf(v[3]);
  ((u16x4*)dst)[i] = o;
}

// ---------------- K0b: write identity pad matrices ----------------
__global__ void k_eye(unsigned short* __restrict__ H){
  int t = blockIdx.x * 256 + threadIdx.x;       // B*4*1024 = 32768
  int b = t >> 12;
  int r = t & 4095;
  int which = r >> 10;
  int ij = r & 1023;
  int p = (which < 2) ? which : (2048 + which);
  H[((size_t)(b * LPAD + p) << 10) + ij] = ((ij >> 5) == (ij & 31)) ? 0x3F80 : 0;
}

// ---------------- K_wprep: Wa2g[col][e] = bf16(Wa[f][e*5+kk]), col=f*5+kk<25 else 0 ----
__global__ void k_wprep(const float* __restrict__ Wa, unsigned short* __restrict__ Wa2g){
  int t = blockIdx.x * 256 + threadIdx.x;       // 32768 = 32*1024
  int col = t >> 10, e = t & 1023;
  int f = col / 5, kk = col - 5 * f;
  unsigned short v = 0;
  if (col < 25) v = f2bf(Wa[f * 5120 + e * 5 + kk]);
  Wa2g[t] = v;
}

#define MFMA16 __builtin_amdgcn_mfma_f32_16x16x32_bf16

// ---------------- K1: 256x128 tile, 48KB single-buffer LDS, 2 blocks/CU (TLP) ----
// Mechanism: with 2 independent blocks per CU, one block's vmcnt(0)+barrier drain
// is covered by the other block's MFMA phases (m97/m114 implicit overlap).
__global__ __launch_bounds__(512, 4) void k_gemm2(const unsigned short* __restrict__ A,   // [16384][1024]
                                                  const unsigned short* __restrict__ Bw,  // [1024][1024]
                                                  const float* __restrict__ bias,
                                                  unsigned short* __restrict__ H){
  __shared__ __align__(128) unsigned short lds[24576];  // 48KB: A 32KB | B 16KB
  const int tid = threadIdx.x;
  const int wid = tid >> 6, l = tid & 63;
  const int wm = wid >> 1, wn = wid & 1;     // 4x2 wave grid; wave tile 64x64
  const int lm = l & 15, lk = l >> 4;
  const int hb = blockIdx.x;                 // 0..511
  const int xcd = hb & 7, sl = hb >> 3;      // 0..63
  const int bm = xcd * 8 + (sl >> 3), bn = sl & 7;
  const int M0 = bm * 256, N0 = bn * 128;

  // swizzle: 16B chunk c of 128B row stored at chunk c ^ (row&7)  [proven 0-conflict]
  const unsigned ko0 = (unsigned)((lk ^ (lm & 7)) << 4);
  const unsigned ko1 = ko0 ^ 64u;
  const unsigned rA = ((unsigned)(wm * 64 + lm)) * 128u;           // + m*2048
  const unsigned rB = 32768u + ((unsigned)(wn * 64 + lm)) * 128u;  // + n*2048

  f32x4 acc[4][4] = {};

  for (int kt = 0; kt < 16; ++kt){
    const int ktK = kt * 64;
    #pragma unroll
    for (int j = 0; j < 6; j++){
      unsigned d = (unsigned)(j * 512 + tid) * 16;
      const unsigned short* g;
      if (j < 4){                                   // A region: 32KB
        unsigned row = d >> 7;
        unsigned srcC = ((d >> 4) & 7u) ^ (row & 7u);
        g = A + (size_t)(M0 + row) * 1024 + ktK + srcC * 8;
      } else {                                      // B region: 16KB
        unsigned db = d - 32768u;
        unsigned row = db >> 7;
        unsigned srcC = ((db >> 4) & 7u) ^ (row & 7u);
        g = Bw + (size_t)(N0 + row) * 1024 + ktK + srcC * 8;
      }
      __builtin_amdgcn_global_load_lds((const __attribute__((address_space(1))) void*)g,
                                       (__attribute__((address_space(3))) void*)&lds[d >> 1],
                                       16, 0, 0);
    }
    __syncthreads();   // drains vmcnt(0): tile visible (stall covered by co-resident block)

    s16x8 a0[4], b0[4];   // one shared frag set, reused across K-halves (reg cap)
    #pragma unroll
    for (int m = 0; m < 4; m++) a0[m] = *(const s16x8*)&lds[(rA + m * 2048u + ko0) >> 1];
    #pragma unroll
    for (int n = 0; n < 4; n++) b0[n] = *(const s16x8*)&lds[(rB + n * 2048u + ko0) >> 1];
    #pragma unroll
    for (int m = 0; m < 4; m++){
      #pragma unroll
      for (int n = 0; n < 4; n++)
        acc[m][n] = MFMA16(a0[m], b0[n], acc[m][n], 0, 0, 0);
    }
    #pragma unroll
    for (int m = 0; m < 4; m++) a0[m] = *(const s16x8*)&lds[(rA + m * 2048u + ko1) >> 1];
    #pragma unroll
    for (int n = 0; n < 4; n++) b0[n] = *(const s16x8*)&lds[(rB + n * 2048u + ko1) >> 1];
    #pragma unroll
    for (int m = 0; m < 4; m++){
      #pragma unroll
      for (int n = 0; n < 4; n++)
        acc[m][n] = MFMA16(a0[m], b0[n], acc[m][n], 0, 0, 0);
    }
    __syncthreads();   // all reads done before next stage overwrites
  }

  // epilogue: h = acc + bias -> bf16 H
  float bv[4];
  #pragma unroll
  for (int n = 0; n < 4; n++) bv[n] = bias[N0 + wn * 64 + n * 16 + lm];
  #pragma unroll
  for (int m = 0; m < 4; m++){
    #pragma unroll
    for (int r = 0; r < 4; r++){
      int gm = M0 + wm * 64 + m * 16 + lk * 4 + r;
      int bb = gm >> 11, li = gm & 2047;
      unsigned short* orow = H + ((size_t)(bb * LPAD + 2 + li) << 10);
      #pragma unroll
      for (int n = 0; n < 4; n++){
        orow[N0 + wn * 64 + n * 16 + lm] = f2bf(acc[m][n][r] + bv[n]);
      }
    }
  }
}

// ---------------- K2: part[p][0..31] = <Hpad[p], Wa2g[col]>  (thin MFMA GEMM) ----------------
__global__ __launch_bounds__(256) void k_part(const unsigned short* __restrict__ H,    // [16416][1024]
                                              const unsigned short* __restrict__ Wa2g, // [32][1024]
                                              float* __restrict__ part){               // [16512][32]
  __shared__ unsigned short sB[32768];  // [32 col][1024 k], chunk c at c^(col&7)
  const int tid = threadIdx.x;
  const int wv = tid >> 6, l = tid & 63;
  const int lm = l & 15, lk = l >> 4;
  #pragma unroll
  for (int j = 0; j < 16; j++){
    unsigned d = (unsigned)(j * 256 + tid) * 16;
    unsigned col = d >> 11;
    unsigned srcC = ((d >> 4) & 127u) ^ (col & 7u);
    const unsigned short* g = Wa2g + col * 1024 + srcC * 8;
    __builtin_amdgcn_global_load_lds((const __attribute__((address_space(1))) void*)g,
                                     (__attribute__((address_space(3))) void*)&sB[d >> 1],
                                     16, 0, 0);
  }
  __syncthreads();
  const int rbase = blockIdx.x * 128 + wv * 32;
  f32x4 acc[2][2] = {};
  for (int kk = 0; kk < 1024; kk += 32){
    s16x8 aF[2], bF[2];
    #pragma unroll
    for (int m = 0; m < 2; m++)
      aF[m] = *(const s16x8*)(H + (size_t)(rbase + m * 16 + lm) * 1024 + kk + lk * 8);
    #pragma unroll
    for (int n = 0; n < 2; n++){
      unsigned col = (unsigned)(n * 16 + lm);
      unsigned c = (unsigned)(kk >> 3) + (unsigned)lk;
      bF[n] = *(const s16x8*)&sB[(col * 2048u + ((c ^ (col & 7u)) << 4)) >> 1];
    }
    #pragma unroll
    for (int m = 0; m < 2; m++){
      #pragma unroll
      for (int n = 0; n < 2; n++)
        acc[m][n] = MFMA16(aF[m], bF[n], acc[m][n], 0, 0, 0);
    }
  }
  #pragma unroll
  for (int m = 0; m < 2; m++){
    #pragma unroll
    for (int r = 0; r < 4; r++){
      int row = rbase + m * 16 + lk * 4 + r;
      #pragma unroll
      for (int n = 0; n < 2; n++)
        part[(size_t)row * 32 + n * 16 + lm] = acc[m][n][r];
    }
  }
}

// ---------------- K4: softmax (from part) + 32x32 matrix chain, scaled by s ----------------
__global__ __launch_bounds__(256) void k_chain(const unsigned short* __restrict__ H,
                                               const float* __restrict__ part,
                                               const float* __restrict__ battn,
                                               float* __restrict__ out){
  const int tid = threadIdx.x;
  const int w = tid >> 6, l = tid & 63;
  const int blk = (blockIdx.x & 7) * 512 + (blockIdx.x >> 3);
  const int pos = blk * 4 + w;
  const int bb = pos >> 11, li = pos & 2047;
  const unsigned short* hbase = H + ((size_t)(bb * LPAD + li) << 10);
  const int col = l & 31;
  const int kh = (l >> 5) << 3;

  const float* prow = part + (size_t)(bb * LPAD + li) * 32;
  float sc[5];
  #pragma unroll
  for (int f = 0; f < 5; f++){
    float a = battn[f];
    #pragma unroll
    for (int k = 0; k < 5; k++)
      a += prow[k * 32 + f * 5 + k];
    sc[f] = (a > 0.f) ? a : 0.01f * a;
  }
  float mx = sc[0];
  #pragma unroll
  for (int f = 1; f < 5; f++) mx = fmaxf(mx, sc[f]);
  float e0 = expf(sc[0] - mx), e1 = expf(sc[1] - mx), e2 = expf(sc[2] - mx),
        e3 = expf(sc[3] - mx), e4 = expf(sc[4] - mx);
  float ssum = e0 + e1 + e2 + e3 + e4;
  float inv = 1.f / ssum;
  float inv2 = inv * inv;
  const float sv = (e0 * e1 * e2 * e3 * e4) * inv2 * inv2 * inv;

  const unsigned short* h4 = hbase + 4 * 1024;
  unsigned q0, q1, q2, q3, q4, q5, q6, q7;
  {
    #define LD2(kk) ((unsigned)h4[(kk) * 32 + col] | ((unsigned)h4[((kk) + 1) * 32 + col] << 16))
    q0 = LD2(kh + 0);  q1 = LD2(kh + 2);  q2 = LD2(kh + 4);  q3 = LD2(kh + 6);
    q4 = LD2(kh + 16); q5 = LD2(kh + 18); q6 = LD2(kh + 20); q7 = LD2(kh + 22);
    #undef LD2
  }
  union { unsigned u[4]; s16x8 v; } ub0, ub1;
  ub0.u[0] = q0; ub0.u[1] = q1; ub0.u[2] = q2; ub0.u[3] = q3;
  ub1.u[0] = q4; ub1.u[1] = q5; ub1.u[2] = q6; ub1.u[3] = q7;
  s16x8 Bf0 = ub0.v, Bf1 = ub1.v;

  f32x16 acc;
  #pragma unroll
  for (int st = 0; st < 4; st++){
    const int km = 3 - st;
    const unsigned short* hA = hbase + (km << 10);
    s16x8 A0 = *(const s16x8*)(hA + col * 32 + kh);
    s16x8 A1 = *(const s16x8*)(hA + col * 32 + kh + 16);
    f32x16 z = {0,0,0,0,0,0,0,0,0,0,0,0,0,0,0,0};
    acc = __builtin_amdgcn_mfma_f32_32x32x16_bf16(A0, Bf0, z,   0, 0, 0);
    acc = __builtin_amdgcn_mfma_f32_32x32x16_bf16(A1, Bf1, acc, 0, 0, 0);
    if (st < 3){
      unsigned d0 = cvt_pk_bf16(acc[0],  acc[1]);
      unsigned d1 = cvt_pk_bf16(acc[2],  acc[3]);
      unsigned d2 = cvt_pk_bf16(acc[4],  acc[5]);
      unsigned d3 = cvt_pk_bf16(acc[6],  acc[7]);
      unsigned d4 = cvt_pk_bf16(acc[8],  acc[9]);
      unsigned d5 = cvt_pk_bf16(acc[10], acc[11]);
      unsigned d6 = cvt_pk_bf16(acc[12], acc[13]);
      unsigned d7 = cvt_pk_bf16(acc[14], acc[15]);
      unsigned p0 = __shfl_xor(d0, 32, 64);
      unsigned p1 = __shfl_xor(d1, 32, 64);
      unsigned p2 = __shfl_xor(d2, 32, 64);
      unsigned p3 = __shfl_xor(d3, 32, 64);
      unsigned p4 = __shfl_xor(d4, 32, 64);
      unsigned p5 = __shfl_xor(d5, 32, 64);
      unsigned p6 = __shfl_xor(d6, 32, 64);
      unsigned p7 = __shfl_xor(d7, 32, 64);
      const bool lo = (l < 32);
      ub0.u[0] = lo ? d0 : p2;  ub0.u[1] = lo ? d1 : p3;
      ub0.u[2] = lo ? p0 : d2;  ub0.u[3] = lo ? p1 : d3;
      ub1.u[0] = lo ? d4 : p6;  ub1.u[1] = lo ? d5 : p7;
      ub1.u[2] = lo ? p4 : d6;  ub1.u[3] = lo ? p5 : d7;
      Bf0 = ub0.v; Bf1 = ub1.v;
    }
  }

  float* ob = out + ((size_t)pos << 10);
  #pragma unroll
  for (int t = 0; t < 16; t++){
    int row = (t & 3) + 8 * (t >> 2) + ((l >> 5) << 2);
    ob[row * 32 + col] = sv * acc[t];
  }
}

// ---------------- launcher ----------------
extern "C" void kernel_launch(void* const* d_in, const int* in_sizes, int n_in,
                              void* d_out, int out_size, void* d_ws, size_t ws_size,
                              hipStream_t stream){
  const float* X  = (const float*)d_in[0];
  const float* Wd = (const float*)d_in[1];
  const float* bd = (const float*)d_in[2];
  const float* Wa = (const float*)d_in[3];
  const float* ba = (const float*)d_in[4];
  float* out = (float*)d_out;

  char* ws = (char*)d_ws;
  unsigned short* Hpad = (unsigned short*)ws;                               // 33,619,968 B
  unsigned short* Wbf  = (unsigned short*)(ws + 33619968);                  // 2,097,152 B
  unsigned short* Wa2g = (unsigned short*)(ws + 33619968 + 2097152);        // 65,536 B
  float*          part = (float*)(ws + 33619968 + 2097152 + 65536);         // 2,113,536 B
  // scratch parked in d_out (consumed by k_gemm2 before k_chain writes):
  unsigned short* Xbf  = (unsigned short*)d_out;                            // [0, 33,554,432)

  k_cvtx<<<16384, 256, 0, stream>>>(X, Xbf);
  k_cvt<<<1024, 256, 0, stream>>>(Wd, Wbf, 262144);
  k_eye<<<128, 256, 0, stream>>>(Hpad);
  k_wprep<<<128, 256, 0, stream>>>(Wa, Wa2g);
  k_gemm2<<<512, 512, 0, stream>>>(Xbf, Wbf, bd, Hpad);
  k_part<<<129, 256, 0, stream>>>(Hpad, Wa2g, part);
  k_chain<<<4096, 256, 0, stream>>>(Hpad, part, ba, out);
}